// Round 7
// baseline (2330.977 us; speedup 1.0000x reference)
//
#include <hip/hip_runtime.h>
#include <hip/hip_bf16.h>

// ConvLSTM (2 layers) on MI355X. R18 = R16 (2117us, best) + 2-deep B-operand prefetch.
// R17 post-mortem: full unroll + bounds(256,3) regressed (icache + L2 overcommit,
// WRITE 61->95MB); VALU theory falsified (VALUBusy unchanged). Reverted.
// R18 theory: B fragments come from L2 (~250cy) but were prefetched only 1 tap
// (~80cy of MFMA) ahead -> ~150cy stall per tap x 45 taps, waves stall in phase.
// Explicit 3-register-set rotation (b0/b1/b2): tap t consumes weights issued at
// t-2 (~240cy cover). +16 VGPR, same occupancy tier. Single-variable change.
// Kept from R16: nt-grouped XCD stripe swizzle (FETCH 100->54MB), tail-less 5-DMA
// halo staging, P (B,64,64,160) fp16 [x(1),h0(128),h1(12),pad], wave tile 64x64,
// acc 4x4, dbuf 40960B LDS, launch_bounds(256,2), runtime ch loop, tanhf.

typedef __attribute__((ext_vector_type(8))) short short8;
typedef __attribute__((ext_vector_type(4))) float float4v;

#define CS 160
#define KTOT 1440         // 9*160
#define RSTR 2560         // LDS halo row stride (shorts) = 5 * 64 lanes * 8
#define BSTR 10240        // LDS buffer stride (shorts) = 4 * RSTR

__device__ __forceinline__ float sigf(float x) { return 1.f / (1.f + __expf(-x)); }
__device__ __forceinline__ short f2hs(float v) {
  _Float16 h = (_Float16)v;
  return *(short*)&h;
}
__device__ __forceinline__ float bs2f(short s) {
  __hip_bfloat16 h; *(short*)&h = s; return __bfloat162float(h);
}
__device__ __forceinline__ short f2bs(float v) {
  __hip_bfloat16 h = __float2bfloat16(v);
  return *(short*)&h;
}

// async 16B global->LDS; per-lane lds ptr must equal uniform_base + lane*16
__device__ __forceinline__ void async_ld16(const short* g, short* l) {
  __builtin_amdgcn_global_load_lds(
      (const __attribute__((address_space(1))) unsigned int*)g,
      (__attribute__((address_space(3))) unsigned int*)l, 16, 0, 0);
}

// Stage one halo row (66 px x 32 ch) into LDS at dstRow (row-major, 32ch/px),
// 5 wave-level DMAs, NO register loads (no vmcnt drain inside the stage).
__device__ __forceinline__ void stage_row(const short* __restrict__ rowPtr, bool rowOK,
                                          short* dstRow, int lane,
                                          const short* __restrict__ zp) {
  #pragma unroll
  for (int j = 0; j < 5; ++j) {
    int e = j * 64 + lane;
    int px = e >> 2, v = e & 3;
    int xx = px - 1;
    bool ok = rowOK && (px < 66) && (xx >= 0) && (xx < 64);
    const short* g = ok ? (rowPtr + (size_t)xx * CS + v * 8) : zp;
    async_ld16(g, dstRow + e * 8);
  }
}

// ---- dtype detect: fp32 low-halves have uniform bits[14:7]; bf16 weights cluster ----
__global__ void detect_dtype(const unsigned short* __restrict__ w0, int* __restrict__ flag) {
  int lane = threadIdx.x;
  int cnt = 0;
  for (int i = 0; i < 4; ++i) {
    unsigned short u = w0[2 * (lane + 64 * i)];
    int e = (u >> 7) & 0xFF;
    unsigned long long b = __ballot(e >= 0xC0);
    cnt += __popcll(b);
  }
  if (lane == 0) *flag = (cnt > 32) ? 1 : 0;   // 1 = fp32 inputs
}

// ---- canonicalize x -> fp16 shorts (bf16->fp16 exact; sanitized) ----
__global__ void canon_x(const void* __restrict__ hist, short* __restrict__ Xc,
                        const int* __restrict__ flag) {
  int i = blockIdx.x * 256 + threadIdx.x;      // < 786432
  float v = (*flag) ? ((const float*)hist)[i] : bs2f(((const short*)hist)[i]);
  if (!isfinite(v) || fabsf(v) > 1e4f) v = 0.f;
  Xc[i] = f2hs(v);
}

__global__ void canon_b(const void* __restrict__ b0, const void* __restrict__ b1,
                        float* __restrict__ Bc0, float* __restrict__ Bc1,
                        const int* __restrict__ flag) {
  int i = blockIdx.x * 256 + threadIdx.x;
  int fl = *flag;
  if (i < 512) {
    float v = fl ? ((const float*)b0)[i] : bs2f(((const short*)b0)[i]);
    if (!isfinite(v) || fabsf(v) > 1e4f) v = 0.f;
    Bc0[i] = v;
  } else if (i < 560) {
    int j = i - 512;
    float v = fl ? ((const float*)b1)[j] : bs2f(((const short*)b1)[j]);
    if (!isfinite(v) || fabsf(v) > 1e4f) v = 0.f;
    Bc1[j] = v;
  }
}

// layer0 W0 (512,129,3,3) -> fp16 Wp[co][tap*160+c]: P-ch 0=x, 1..128=h0, else 0.
__global__ void prep_w0(const void* __restrict__ W0, short* __restrict__ Wp,
                        const int* __restrict__ flag) {
  int i = blockIdx.x * 256 + threadIdx.x;
  if (i >= 512 * KTOT) return;
  int fl = *flag;
  int co = i / KTOT, k = i - co * KTOT;
  int tap = k / CS, c = k - tap * CS;
  int ci = -1;
  if (c == 0) ci = 0;
  else if (c <= 128) ci = c;
  float w = 0.f;
  if (ci >= 0) {
    int widx = (co * 129 + ci) * 9 + tap;
    w = fl ? ((const float*)W0)[widx] : bs2f(((const short*)W0)[widx]);
    if (!isfinite(w) || fabsf(w) > 1e4f) w = 0.f;
  }
  Wp[i] = f2hs(w);
}

// layer1 W1 (48,140,3,3) -> fp16: P-ch 1..128=h0, 129..140=h1, else 0.
__global__ void prep_w1(const void* __restrict__ W1, short* __restrict__ Wp,
                        const int* __restrict__ flag) {
  int i = blockIdx.x * 256 + threadIdx.x;
  if (i >= 48 * KTOT) return;
  int fl = *flag;
  int co = i / KTOT, k = i - co * KTOT;
  int tap = k / CS, c = k - tap * CS;
  int ci = -1;
  if (c >= 1 && c <= 140) ci = c - 1;
  float w = 0.f;
  if (ci >= 0) {
    int widx = (co * 140 + ci) * 9 + tap;
    w = fl ? ((const float*)W1)[widx] : bs2f(((const short*)W1)[widx]);
    if (!isfinite(w) || fabsf(w) > 1e4f) w = 0.f;
  }
  Wp[i] = f2hs(w);
}

__global__ void fill_x0(const short* __restrict__ Xc, short* __restrict__ P0) {
  int p = blockIdx.x * 256 + threadIdx.x;      // b*4096 + pix
  int b = p >> 12, pix = p & 4095;
  P0[(size_t)p * CS] = Xc[b * 12 * 4096 + pix];
}

// ---- layer 0: M=128px (2 rows) x N=128co (4 gates x 32 hc). Grid = 4 nt * 512 mt. ----
__global__ __launch_bounds__(256, 2) void gemm_gate0(
    const short* __restrict__ Pcur, short* __restrict__ Pnext,
    const short* __restrict__ Wp, const float* __restrict__ Bc0,
    float* __restrict__ C0, const short* __restrict__ Xc,
    const short* __restrict__ zp, int t) {
  // nt-grouped XCD stripe swizzle (R16): XCD x owns mt in [64x,64x+64) for ALL nt.
  int pbx = blockIdx.x;
  int xcd = pbx & 7, i = pbx >> 3;
  int mt = xcd * 64 + (i & 63);
  int nt = i >> 6;
  int b = mt >> 5, y0 = (mt & 31) * 2;
  int tid = threadIdx.x, wave = tid >> 6, lane = tid & 63;
  int ln15 = lane & 15, quad = lane >> 4;
  int wm = wave & 1, wn = wave >> 1;
  int hc = nt * 32 + wn * 16 + ln15;

  __shared__ __align__(16) short halo[2 * BSTR];   // dbuf, 40960 B

  float4v acc[4][4];
  #pragma unroll
  for (int i2 = 0; i2 < 4; ++i2)
    #pragma unroll
    for (int j = 0; j < 4; ++j) acc[i2][j] = (float4v){0.f, 0.f, 0.f, 0.f};

  // B frag addr (g, tap, c0): wbase + g*128*KTOT + tap*CS + c0.
  // 2-deep rotation: b0v = tap t (consume), b1v = tap t+1, b2v = tap t+2 (issue).
  const short* wbase = Wp + (size_t)hc * KTOT + quad * 8;
  short8 b0v[4], b1v[4];
  #pragma unroll
  for (int g = 0; g < 4; ++g) {
    b0v[g] = *(const short8*)(wbase + (size_t)g * 128 * KTOT);        // tap0, c0=0
    b1v[g] = *(const short8*)(wbase + (size_t)g * 128 * KTOT + CS);   // tap1, c0=0
  }

  int yy = y0 - 1 + wave;
  bool rowOK = (yy >= 0) && (yy < 64);
  const short* rowBase = Pcur + (size_t)((b * 64 + yy) * 64) * CS;

  stage_row(rowBase, rowOK, halo + wave * RSTR, lane, zp);
  __syncthreads();

  for (int ch = 0; ch < 5; ++ch) {
    int c0 = ch * 32;
    const short* cur = halo + (ch & 1) * BSTR;
    if (ch < 4)
      stage_row(rowBase + c0 + 32, rowOK, halo + ((ch + 1) & 1) * BSTR + wave * RSTR,
                lane, zp);
    #pragma unroll
    for (int tap = 0; tap < 9; ++tap) {
      int dy = tap / 3, dx = tap - dy * 3;
      // issue tap+2 B fragments (crosses into next chunk for taps 7,8)
      int ptap = tap + 2, pc0 = c0;
      if (ptap >= 9) { ptap -= 9; pc0 = (ch < 4) ? c0 + 32 : c0; }
      short8 b2v[4];
      #pragma unroll
      for (int g = 0; g < 4; ++g)
        b2v[g] = *(const short8*)(wbase + (size_t)g * 128 * KTOT + ptap * CS + pc0);

      short8 af[4];
      #pragma unroll
      for (int mf = 0; mf < 4; ++mf)
        af[mf] = *(const short8*)&cur[(wm + dy) * RSTR + (mf * 16 + ln15 + dx) * 32 + quad * 8];
      #pragma unroll
      for (int g = 0; g < 4; ++g)
        #pragma unroll
        for (int mf = 0; mf < 4; ++mf)
          acc[mf][g] = __builtin_amdgcn_mfma_f32_16x16x32_f16(af[mf], b0v[g], acc[mf][g], 0, 0, 0);
      #pragma unroll
      for (int g = 0; g < 4; ++g) { b0v[g] = b1v[g]; b1v[g] = b2v[g]; }
    }
    __syncthreads();
  }

  // epilogue: all 4 gates in-register per (pix,hc)
  float bi = Bc0[hc], bff = Bc0[128 + hc], bo = Bc0[256 + hc], bg = Bc0[384 + hc];
  int rowPix = (b * 64 + y0 + wm) * 64;
  #pragma unroll
  for (int mf = 0; mf < 4; ++mf) {
    #pragma unroll
    for (int r = 0; r < 4; ++r) {
      int x = mf * 16 + quad * 4 + r;          // C/D row = quad*4 + reg
      int pix = rowPix + x;
      float zi = acc[mf][0][r] + bi;
      float zf = acc[mf][1][r] + bff;
      float zo = acc[mf][2][r] + bo;
      float zg = acc[mf][3][r] + bg;
      float cprev = C0[(size_t)pix * 128 + hc];
      float cn = sigf(zf) * cprev + sigf(zi) * tanhf(zg);
      float hn = sigf(zo) * tanhf(cn);
      C0[(size_t)pix * 128 + hc] = cn;
      Pnext[(size_t)pix * CS + 1 + hc] = f2hs(hn);
    }
  }
  if (nt == 0 && t < 11 && tid < 128) {
    int rr = tid >> 6, x = tid & 63;
    int yw = y0 + rr;
    Pnext[(size_t)((b * 64 + yw) * 64 + x) * CS] = Xc[(b * 12 + t + 1) * 4096 + yw * 64 + x];
  }
}

// ---- layer 1: M=128px (2 rows) x N=48co. Grid 512. 2-deep B prefetch. ----
__global__ __launch_bounds__(256, 2) void gemm_gate1(
    const short* __restrict__ Prd, short* __restrict__ Pwr,
    const short* __restrict__ Wp, const float* __restrict__ Bc1,
    float* __restrict__ C1, void* __restrict__ outp,
    const short* __restrict__ zp, const int* __restrict__ flagp, int t) {
  // XCD stripe swizzle: XCD x owns bid in [64x, 64x+64) = 2 batches (L2-fit halos).
  int pbx = blockIdx.x;
  int bid = (pbx & 7) * 64 + (pbx >> 3);
  int b = bid >> 5, y0 = (bid & 31) * 2;
  int tid = threadIdx.x, wave = tid >> 6, lane = tid & 63;
  int ln15 = lane & 15, quad = lane >> 4;
  int wr = wave >> 1, wh = wave & 1;
  int flagv = *flagp;

  __shared__ __align__(16) short halo[2 * BSTR];   // 40960 B

  float4v acc[2][3];
  #pragma unroll
  for (int i = 0; i < 2; ++i)
    #pragma unroll
    for (int j = 0; j < 3; ++j) acc[i][j] = (float4v){0.f, 0.f, 0.f, 0.f};

  int yy = y0 - 1 + wave;
  bool rowOK = (yy >= 0) && (yy < 64);
  const short* rowBase = Prd + (size_t)((b * 64 + yy) * 64) * CS;

  const short* wbase = Wp + (size_t)ln15 * KTOT + quad * 8;
  short8 b0v[3], b1v[3];
  #pragma unroll
  for (int nf = 0; nf < 3; ++nf) {
    b0v[nf] = *(const short8*)(wbase + (size_t)nf * 16 * KTOT);        // tap0, c0=0
    b1v[nf] = *(const short8*)(wbase + (size_t)nf * 16 * KTOT + CS);   // tap1, c0=0
  }

  stage_row(rowBase, rowOK, halo + wave * RSTR, lane, zp);
  __syncthreads();

  for (int ch = 0; ch < 5; ++ch) {
    int c0 = ch * 32;
    const short* cur = halo + (ch & 1) * BSTR;
    if (ch < 4)
      stage_row(rowBase + c0 + 32, rowOK, halo + ((ch + 1) & 1) * BSTR + wave * RSTR,
                lane, zp);
    #pragma unroll
    for (int tap = 0; tap < 9; ++tap) {
      int dy = tap / 3, dx = tap - dy * 3;
      int ptap = tap + 2, pc0 = c0;
      if (ptap >= 9) { ptap -= 9; pc0 = (ch < 4) ? c0 + 32 : c0; }
      short8 b2v[3];
      #pragma unroll
      for (int nf = 0; nf < 3; ++nf)
        b2v[nf] = *(const short8*)(wbase + (size_t)nf * 16 * KTOT + ptap * CS + pc0);

      short8 af[2];
      #pragma unroll
      for (int mf = 0; mf < 2; ++mf)
        af[mf] = *(const short8*)&cur[(wr + dy) * RSTR + (wh * 32 + mf * 16 + ln15 + dx) * 32
                                      + quad * 8];
      #pragma unroll
      for (int nf = 0; nf < 3; ++nf)
        #pragma unroll
        for (int mf = 0; mf < 2; ++mf)
          acc[mf][nf] = __builtin_amdgcn_mfma_f32_16x16x32_f16(af[mf], b0v[nf], acc[mf][nf], 0, 0, 0);
      #pragma unroll
      for (int nf = 0; nf < 3; ++nf) { b0v[nf] = b1v[nf]; b1v[nf] = b2v[nf]; }
    }
    __syncthreads();
  }

  // z -> LDS (reuse halo: 128*48 fp32 = 24576 B), then gate pass
  float* zbuf = (float*)halo;
  #pragma unroll
  for (int mf = 0; mf < 2; ++mf)
    #pragma unroll
    for (int nf = 0; nf < 3; ++nf)
      #pragma unroll
      for (int r = 0; r < 4; ++r) {
        int pxl = wr * 64 + wh * 32 + mf * 16 + quad * 4 + r;
        zbuf[pxl * 48 + nf * 16 + ln15] = acc[mf][nf][r];
      }
  __syncthreads();

  #pragma unroll
  for (int k = 0; k < 6; ++k) {
    int id = k * 256 + tid;
    int hc = id >> 7, pxl = id & 127;
    float zi = zbuf[pxl * 48 + hc]      + Bc1[hc];
    float zf = zbuf[pxl * 48 + 12 + hc] + Bc1[12 + hc];
    float zo = zbuf[pxl * 48 + 24 + hc] + Bc1[24 + hc];
    float zg = zbuf[pxl * 48 + 36 + hc] + Bc1[36 + hc];
    int y = y0 + (pxl >> 6), x = pxl & 63;
    int pix = (b * 64 + y) * 64 + x;
    float cprev = C1[(size_t)pix * 12 + hc];
    float cn = sigf(zf) * cprev + sigf(zi) * tanhf(zg);
    float hn = sigf(zo) * tanhf(cn);
    C1[(size_t)pix * 12 + hc] = cn;
    Pwr[(size_t)pix * CS + 129 + hc] = f2hs(hn);
    if (t == 11) {
      int oidx = (b * 12 + hc) * 4096 + y * 64 + x;
      if (flagv) ((float*)outp)[oidx] = hn;
      else ((short*)outp)[oidx] = f2bs(hn);
    }
  }
}

extern "C" void kernel_launch(void* const* d_in, const int* in_sizes, int n_in,
                              void* d_out, int out_size, void* d_ws, size_t ws_size,
                              hipStream_t stream) {
  const void* hist = d_in[0];                  // (16,12,4096,1)
  const void* W0 = d_in[2];                    // (512,129,3,3)
  const void* b0 = d_in[3];
  const void* W1 = d_in[4];                    // (48,140,3,3)
  const void* b1 = d_in[5];

  char* ws = (char*)d_ws;
  const size_t PszB = (size_t)16 * 4096 * CS * 2;     // 20,971,520
  short* P[2] = {(short*)ws, (short*)(ws + PszB)};
  float* C0 = (float*)(ws + 2 * PszB);                // 33,554,432
  const size_t C0e = 2 * PszB + 33554432;
  float* C1 = (float*)(ws + C0e);                     // 3,145,728
  const size_t C1e = C0e + 3145728;
  short* zp = (short*)(ws + C1e);                     // 256 B zero page
  const size_t zpe = C1e + 256;
  short* Xc = (short*)(ws + zpe);                     // 1,572,864
  const size_t Xce = zpe + 1572864;
  short* Wp0 = (short*)(ws + Xce);                    // 512*1440*2 = 1,474,560
  const size_t W0e = Xce + (size_t)512 * KTOT * 2;
  short* Wp1 = (short*)(ws + W0e);                    // 48*1440*2 = 138,240
  const size_t W1e = W0e + (size_t)48 * KTOT * 2;
  float* Bc0 = (float*)(ws + W1e);                    // 2048
  float* Bc1 = (float*)(ws + W1e + 2048);             // 192
  int* flag = (int*)(ws + W1e + 2048 + 192);          // total ~82 MiB

  hipMemsetAsync(ws, 0, zpe, stream);                 // P pair + C0 + C1 + zero page
  detect_dtype<<<1, 64, 0, stream>>>((const unsigned short*)W0, flag);
  canon_x<<<3072, 256, 0, stream>>>(hist, Xc, flag);
  canon_b<<<3, 256, 0, stream>>>(b0, b1, Bc0, Bc1, flag);
  prep_w0<<<(512 * KTOT + 255) / 256, 256, 0, stream>>>(W0, Wp0, flag);
  prep_w1<<<(48 * KTOT + 255) / 256, 256, 0, stream>>>(W1, Wp1, flag);
  fill_x0<<<256, 256, 0, stream>>>(Xc, P[0]);

  for (int t = 0; t < 12; ++t) {
    gemm_gate0<<<2048, 256, 0, stream>>>(P[t & 1], P[(t + 1) & 1], Wp0, Bc0, C0, Xc, zp, t);
    gemm_gate1<<<512, 256, 0, stream>>>(P[(t + 1) & 1], P[t & 1], Wp1, Bc1, C1,
                                        d_out, zp, flag, t);
  }
}

// Round 8
// 2089.870 us; speedup vs baseline: 1.1154x; 1.1154x over previous
//
#include <hip/hip_runtime.h>
#include <hip/hip_bf16.h>

// ConvLSTM (2 layers) on MI355X. R19 = R16 (best, 2117us) + spread halo staging.
// vmcnt is ONE in-order FIFO: R16 issued all 5 next-chunk DMAs at chunk top, so
// tap1's wait for bcur (loaded tap0) transitively drained ALL staging DMAs --
// right after the barrier, with all waves in phase (no cross-wave hiding).
// R18 (deeper B prefetch) regressed because it fed MORE loads into the same FIFO.
// Fix: issue ONE staging DMA per tap (taps 0..4). Each per-tap B-wait then only
// retires one DMA issued a full tap (~490cy) earlier -- covered for L2 hits.
// Plain-HIP analog of AITER's interleaved MFMA<->load with counted vmcnt.
// Kept from R16: nt-grouped XCD stripe swizzle (FETCH 100->54MB), tail-less DMA
// rows, P (B,64,64,160) fp16 [x(1),h0(128),h1(12),pad], wave tile 64x64, acc 4x4,
// 1-tap B reg prefetch, dbuf 40960B LDS, launch_bounds(256,2), runtime ch loop.

typedef __attribute__((ext_vector_type(8))) short short8;
typedef __attribute__((ext_vector_type(4))) float float4v;

#define CS 160
#define KTOT 1440         // 9*160
#define RSTR 2560         // LDS halo row stride (shorts) = 5 * 64 lanes * 8
#define BSTR 10240        // LDS buffer stride (shorts) = 4 * RSTR

__device__ __forceinline__ float sigf(float x) { return 1.f / (1.f + __expf(-x)); }
__device__ __forceinline__ short f2hs(float v) {
  _Float16 h = (_Float16)v;
  return *(short*)&h;
}
__device__ __forceinline__ float bs2f(short s) {
  __hip_bfloat16 h; *(short*)&h = s; return __bfloat162float(h);
}
__device__ __forceinline__ short f2bs(float v) {
  __hip_bfloat16 h = __float2bfloat16(v);
  return *(short*)&h;
}

// async 16B global->LDS; per-lane lds ptr must equal uniform_base + lane*16
__device__ __forceinline__ void async_ld16(const short* g, short* l) {
  __builtin_amdgcn_global_load_lds(
      (const __attribute__((address_space(1))) unsigned int*)g,
      (__attribute__((address_space(3))) unsigned int*)l, 16, 0, 0);
}

// One 64-lane DMA slice (j in 0..4) of a halo row (66 px x 32 ch, row-major 32ch/px).
__device__ __forceinline__ void stage_one(const short* __restrict__ rowPtr, bool rowOK,
                                          short* dstRow, int lane,
                                          const short* __restrict__ zp, int j) {
  int e = j * 64 + lane;
  int px = e >> 2, v = e & 3;
  int xx = px - 1;
  bool ok = rowOK && (px < 66) && (xx >= 0) && (xx < 64);
  const short* g = ok ? (rowPtr + (size_t)xx * CS + v * 8) : zp;
  async_ld16(g, dstRow + e * 8);
}

// Full 5-DMA stage (prologue only).
__device__ __forceinline__ void stage_row(const short* __restrict__ rowPtr, bool rowOK,
                                          short* dstRow, int lane,
                                          const short* __restrict__ zp) {
  #pragma unroll
  for (int j = 0; j < 5; ++j) stage_one(rowPtr, rowOK, dstRow, lane, zp, j);
}

// ---- dtype detect: fp32 low-halves have uniform bits[14:7]; bf16 weights cluster ----
__global__ void detect_dtype(const unsigned short* __restrict__ w0, int* __restrict__ flag) {
  int lane = threadIdx.x;
  int cnt = 0;
  for (int i = 0; i < 4; ++i) {
    unsigned short u = w0[2 * (lane + 64 * i)];
    int e = (u >> 7) & 0xFF;
    unsigned long long b = __ballot(e >= 0xC0);
    cnt += __popcll(b);
  }
  if (lane == 0) *flag = (cnt > 32) ? 1 : 0;   // 1 = fp32 inputs
}

// ---- canonicalize x -> fp16 shorts (bf16->fp16 exact; sanitized) ----
__global__ void canon_x(const void* __restrict__ hist, short* __restrict__ Xc,
                        const int* __restrict__ flag) {
  int i = blockIdx.x * 256 + threadIdx.x;      // < 786432
  float v = (*flag) ? ((const float*)hist)[i] : bs2f(((const short*)hist)[i]);
  if (!isfinite(v) || fabsf(v) > 1e4f) v = 0.f;
  Xc[i] = f2hs(v);
}

__global__ void canon_b(const void* __restrict__ b0, const void* __restrict__ b1,
                        float* __restrict__ Bc0, float* __restrict__ Bc1,
                        const int* __restrict__ flag) {
  int i = blockIdx.x * 256 + threadIdx.x;
  int fl = *flag;
  if (i < 512) {
    float v = fl ? ((const float*)b0)[i] : bs2f(((const short*)b0)[i]);
    if (!isfinite(v) || fabsf(v) > 1e4f) v = 0.f;
    Bc0[i] = v;
  } else if (i < 560) {
    int j = i - 512;
    float v = fl ? ((const float*)b1)[j] : bs2f(((const short*)b1)[j]);
    if (!isfinite(v) || fabsf(v) > 1e4f) v = 0.f;
    Bc1[j] = v;
  }
}

// layer0 W0 (512,129,3,3) -> fp16 Wp[co][tap*160+c]: P-ch 0=x, 1..128=h0, else 0.
__global__ void prep_w0(const void* __restrict__ W0, short* __restrict__ Wp,
                        const int* __restrict__ flag) {
  int i = blockIdx.x * 256 + threadIdx.x;
  if (i >= 512 * KTOT) return;
  int fl = *flag;
  int co = i / KTOT, k = i - co * KTOT;
  int tap = k / CS, c = k - tap * CS;
  int ci = -1;
  if (c == 0) ci = 0;
  else if (c <= 128) ci = c;
  float w = 0.f;
  if (ci >= 0) {
    int widx = (co * 129 + ci) * 9 + tap;
    w = fl ? ((const float*)W0)[widx] : bs2f(((const short*)W0)[widx]);
    if (!isfinite(w) || fabsf(w) > 1e4f) w = 0.f;
  }
  Wp[i] = f2hs(w);
}

// layer1 W1 (48,140,3,3) -> fp16: P-ch 1..128=h0, 129..140=h1, else 0.
__global__ void prep_w1(const void* __restrict__ W1, short* __restrict__ Wp,
                        const int* __restrict__ flag) {
  int i = blockIdx.x * 256 + threadIdx.x;
  if (i >= 48 * KTOT) return;
  int fl = *flag;
  int co = i / KTOT, k = i - co * KTOT;
  int tap = k / CS, c = k - tap * CS;
  int ci = -1;
  if (c >= 1 && c <= 140) ci = c - 1;
  float w = 0.f;
  if (ci >= 0) {
    int widx = (co * 140 + ci) * 9 + tap;
    w = fl ? ((const float*)W1)[widx] : bs2f(((const short*)W1)[widx]);
    if (!isfinite(w) || fabsf(w) > 1e4f) w = 0.f;
  }
  Wp[i] = f2hs(w);
}

__global__ void fill_x0(const short* __restrict__ Xc, short* __restrict__ P0) {
  int p = blockIdx.x * 256 + threadIdx.x;      // b*4096 + pix
  int b = p >> 12, pix = p & 4095;
  P0[(size_t)p * CS] = Xc[b * 12 * 4096 + pix];
}

// ---- layer 0: M=128px (2 rows) x N=128co (4 gates x 32 hc). Grid = 4 nt * 512 mt. ----
__global__ __launch_bounds__(256, 2) void gemm_gate0(
    const short* __restrict__ Pcur, short* __restrict__ Pnext,
    const short* __restrict__ Wp, const float* __restrict__ Bc0,
    float* __restrict__ C0, const short* __restrict__ Xc,
    const short* __restrict__ zp, int t) {
  // nt-grouped XCD stripe swizzle (R16): XCD x owns mt in [64x,64x+64) for ALL nt.
  int pbx = blockIdx.x;
  int xcd = pbx & 7, i = pbx >> 3;
  int mt = xcd * 64 + (i & 63);
  int nt = i >> 6;
  int b = mt >> 5, y0 = (mt & 31) * 2;
  int tid = threadIdx.x, wave = tid >> 6, lane = tid & 63;
  int ln15 = lane & 15, quad = lane >> 4;
  int wm = wave & 1, wn = wave >> 1;
  int hc = nt * 32 + wn * 16 + ln15;

  __shared__ __align__(16) short halo[2 * BSTR];   // dbuf, 40960 B

  float4v acc[4][4];
  #pragma unroll
  for (int i2 = 0; i2 < 4; ++i2)
    #pragma unroll
    for (int j = 0; j < 4; ++j) acc[i2][j] = (float4v){0.f, 0.f, 0.f, 0.f};

  // B frag addr (g, tap, c0): wbase + g*128*KTOT + tap*CS + c0
  const short* wbase = Wp + (size_t)hc * KTOT + quad * 8;
  short8 bcur[4], bnxt[4];
  #pragma unroll
  for (int g = 0; g < 4; ++g)
    bcur[g] = *(const short8*)(wbase + (size_t)g * 128 * KTOT);

  int yy = y0 - 1 + wave;
  bool rowOK = (yy >= 0) && (yy < 64);
  const short* rowBase = Pcur + (size_t)((b * 64 + yy) * 64) * CS;

  stage_row(rowBase, rowOK, halo + wave * RSTR, lane, zp);
  __syncthreads();

  for (int ch = 0; ch < 5; ++ch) {
    int c0 = ch * 32;
    const short* cur = halo + (ch & 1) * BSTR;
    short* nxtDst = halo + ((ch + 1) & 1) * BSTR + wave * RSTR;
    const short* nxtSrc = rowBase + c0 + 32;
    #pragma unroll
    for (int tap = 0; tap < 9; ++tap) {
      int dy = tap / 3, dx = tap - dy * 3;
      // spread staging: one DMA slice per tap (taps 0..4) so no DMA pile-up
      // ever sits ahead of a B-load in the in-order vmcnt FIFO.
      if (ch < 4 && tap < 5)
        stage_one(nxtSrc, rowOK, nxtDst, lane, zp, tap);
      // prefetch next tap's (or next chunk's tap-0) B fragments
      int ntap = (tap < 8) ? tap + 1 : 0;
      int nc0 = (tap < 8) ? c0 : ((ch < 4) ? c0 + 32 : c0);
      #pragma unroll
      for (int g = 0; g < 4; ++g)
        bnxt[g] = *(const short8*)(wbase + (size_t)g * 128 * KTOT + ntap * CS + nc0);

      short8 af[4];
      #pragma unroll
      for (int mf = 0; mf < 4; ++mf)
        af[mf] = *(const short8*)&cur[(wm + dy) * RSTR + (mf * 16 + ln15 + dx) * 32 + quad * 8];
      #pragma unroll
      for (int g = 0; g < 4; ++g)
        #pragma unroll
        for (int mf = 0; mf < 4; ++mf)
          acc[mf][g] = __builtin_amdgcn_mfma_f32_16x16x32_f16(af[mf], bcur[g], acc[mf][g], 0, 0, 0);
      #pragma unroll
      for (int g = 0; g < 4; ++g) bcur[g] = bnxt[g];
    }
    __syncthreads();
  }

  // epilogue: all 4 gates in-register per (pix,hc)
  float bi = Bc0[hc], bff = Bc0[128 + hc], bo = Bc0[256 + hc], bg = Bc0[384 + hc];
  int rowPix = (b * 64 + y0 + wm) * 64;
  #pragma unroll
  for (int mf = 0; mf < 4; ++mf) {
    #pragma unroll
    for (int r = 0; r < 4; ++r) {
      int x = mf * 16 + quad * 4 + r;          // C/D row = quad*4 + reg
      int pix = rowPix + x;
      float zi = acc[mf][0][r] + bi;
      float zf = acc[mf][1][r] + bff;
      float zo = acc[mf][2][r] + bo;
      float zg = acc[mf][3][r] + bg;
      float cprev = C0[(size_t)pix * 128 + hc];
      float cn = sigf(zf) * cprev + sigf(zi) * tanhf(zg);
      float hn = sigf(zo) * tanhf(cn);
      C0[(size_t)pix * 128 + hc] = cn;
      Pnext[(size_t)pix * CS + 1 + hc] = f2hs(hn);
    }
  }
  if (nt == 0 && t < 11 && tid < 128) {
    int rr = tid >> 6, x = tid & 63;
    int yw = y0 + rr;
    Pnext[(size_t)((b * 64 + yw) * 64 + x) * CS] = Xc[(b * 12 + t + 1) * 4096 + yw * 64 + x];
  }
}

// ---- layer 1: M=128px (2 rows) x N=48co. Grid 512. B register-prefetch. ----
__global__ __launch_bounds__(256, 2) void gemm_gate1(
    const short* __restrict__ Prd, short* __restrict__ Pwr,
    const short* __restrict__ Wp, const float* __restrict__ Bc1,
    float* __restrict__ C1, void* __restrict__ outp,
    const short* __restrict__ zp, const int* __restrict__ flagp, int t) {
  // XCD stripe swizzle: XCD x owns bid in [64x, 64x+64) = 2 batches (L2-fit halos).
  int pbx = blockIdx.x;
  int bid = (pbx & 7) * 64 + (pbx >> 3);
  int b = bid >> 5, y0 = (bid & 31) * 2;
  int tid = threadIdx.x, wave = tid >> 6, lane = tid & 63;
  int ln15 = lane & 15, quad = lane >> 4;
  int wr = wave >> 1, wh = wave & 1;
  int flagv = *flagp;

  __shared__ __align__(16) short halo[2 * BSTR];   // 40960 B

  float4v acc[2][3];
  #pragma unroll
  for (int i = 0; i < 2; ++i)
    #pragma unroll
    for (int j = 0; j < 3; ++j) acc[i][j] = (float4v){0.f, 0.f, 0.f, 0.f};

  int yy = y0 - 1 + wave;
  bool rowOK = (yy >= 0) && (yy < 64);
  const short* rowBase = Prd + (size_t)((b * 64 + yy) * 64) * CS;

  const short* wbase = Wp + (size_t)ln15 * KTOT + quad * 8;
  short8 bcur[3], bnxt[3];
  #pragma unroll
  for (int nf = 0; nf < 3; ++nf)
    bcur[nf] = *(const short8*)(wbase + (size_t)nf * 16 * KTOT);

  stage_row(rowBase, rowOK, halo + wave * RSTR, lane, zp);
  __syncthreads();

  for (int ch = 0; ch < 5; ++ch) {
    int c0 = ch * 32;
    const short* cur = halo + (ch & 1) * BSTR;
    short* nxtDst = halo + ((ch + 1) & 1) * BSTR + wave * RSTR;
    const short* nxtSrc = rowBase + c0 + 32;
    #pragma unroll
    for (int tap = 0; tap < 9; ++tap) {
      int dy = tap / 3, dx = tap - dy * 3;
      if (ch < 4 && tap < 5)
        stage_one(nxtSrc, rowOK, nxtDst, lane, zp, tap);
      int ntap = (tap < 8) ? tap + 1 : 0;
      int nc0 = (tap < 8) ? c0 : ((ch < 4) ? c0 + 32 : c0);
      #pragma unroll
      for (int nf = 0; nf < 3; ++nf)
        bnxt[nf] = *(const short8*)(wbase + (size_t)nf * 16 * KTOT + ntap * CS + nc0);

      short8 af[2];
      #pragma unroll
      for (int mf = 0; mf < 2; ++mf)
        af[mf] = *(const short8*)&cur[(wr + dy) * RSTR + (wh * 32 + mf * 16 + ln15 + dx) * 32
                                      + quad * 8];
      #pragma unroll
      for (int nf = 0; nf < 3; ++nf)
        #pragma unroll
        for (int mf = 0; mf < 2; ++mf)
          acc[mf][nf] = __builtin_amdgcn_mfma_f32_16x16x32_f16(af[mf], bcur[nf], acc[mf][nf], 0, 0, 0);
      #pragma unroll
      for (int nf = 0; nf < 3; ++nf) bcur[nf] = bnxt[nf];
    }
    __syncthreads();
  }

  // z -> LDS (reuse halo: 128*48 fp32 = 24576 B), then gate pass
  float* zbuf = (float*)halo;
  #pragma unroll
  for (int mf = 0; mf < 2; ++mf)
    #pragma unroll
    for (int nf = 0; nf < 3; ++nf)
      #pragma unroll
      for (int r = 0; r < 4; ++r) {
        int pxl = wr * 64 + wh * 32 + mf * 16 + quad * 4 + r;
        zbuf[pxl * 48 + nf * 16 + ln15] = acc[mf][nf][r];
      }
  __syncthreads();

  #pragma unroll
  for (int k = 0; k < 6; ++k) {
    int id = k * 256 + tid;
    int hc = id >> 7, pxl = id & 127;
    float zi = zbuf[pxl * 48 + hc]      + Bc1[hc];
    float zf = zbuf[pxl * 48 + 12 + hc] + Bc1[12 + hc];
    float zo = zbuf[pxl * 48 + 24 + hc] + Bc1[24 + hc];
    float zg = zbuf[pxl * 48 + 36 + hc] + Bc1[36 + hc];
    int y = y0 + (pxl >> 6), x = pxl & 63;
    int pix = (b * 64 + y) * 64 + x;
    float cprev = C1[(size_t)pix * 12 + hc];
    float cn = sigf(zf) * cprev + sigf(zi) * tanhf(zg);
    float hn = sigf(zo) * tanhf(cn);
    C1[(size_t)pix * 12 + hc] = cn;
    Pwr[(size_t)pix * CS + 129 + hc] = f2hs(hn);
    if (t == 11) {
      int oidx = (b * 12 + hc) * 4096 + y * 64 + x;
      if (flagv) ((float*)outp)[oidx] = hn;
      else ((short*)outp)[oidx] = f2bs(hn);
    }
  }
}

extern "C" void kernel_launch(void* const* d_in, const int* in_sizes, int n_in,
                              void* d_out, int out_size, void* d_ws, size_t ws_size,
                              hipStream_t stream) {
  const void* hist = d_in[0];                  // (16,12,4096,1)
  const void* W0 = d_in[2];                    // (512,129,3,3)
  const void* b0 = d_in[3];
  const void* W1 = d_in[4];                    // (48,140,3,3)
  const void* b1 = d_in[5];

  char* ws = (char*)d_ws;
  const size_t PszB = (size_t)16 * 4096 * CS * 2;     // 20,971,520
  short* P[2] = {(short*)ws, (short*)(ws + PszB)};
  float* C0 = (float*)(ws + 2 * PszB);                // 33,554,432
  const size_t C0e = 2 * PszB + 33554432;
  float* C1 = (float*)(ws + C0e);                     // 3,145,728
  const size_t C1e = C0e + 3145728;
  short* zp = (short*)(ws + C1e);                     // 256 B zero page
  const size_t zpe = C1e + 256;
  short* Xc = (short*)(ws + zpe);                     // 1,572,864
  const size_t Xce = zpe + 1572864;
  short* Wp0 = (short*)(ws + Xce);                    // 512*1440*2 = 1,474,560
  const size_t W0e = Xce + (size_t)512 * KTOT * 2;
  short* Wp1 = (short*)(ws + W0e);                    // 48*1440*2 = 138,240
  const size_t W1e = W0e + (size_t)48 * KTOT * 2;
  float* Bc0 = (float*)(ws + W1e);                    // 2048
  float* Bc1 = (float*)(ws + W1e + 2048);             // 192
  int* flag = (int*)(ws + W1e + 2048 + 192);          // total ~82 MiB

  hipMemsetAsync(ws, 0, zpe, stream);                 // P pair + C0 + C1 + zero page
  detect_dtype<<<1, 64, 0, stream>>>((const unsigned short*)W0, flag);
  canon_x<<<3072, 256, 0, stream>>>(hist, Xc, flag);
  canon_b<<<3, 256, 0, stream>>>(b0, b1, Bc0, Bc1, flag);
  prep_w0<<<(512 * KTOT + 255) / 256, 256, 0, stream>>>(W0, Wp0, flag);
  prep_w1<<<(48 * KTOT + 255) / 256, 256, 0, stream>>>(W1, Wp1, flag);
  fill_x0<<<256, 256, 0, stream>>>(Xc, P[0]);

  for (int t = 0; t < 12; ++t) {
    gemm_gate0<<<2048, 256, 0, stream>>>(P[t & 1], P[(t + 1) & 1], Wp0, Bc0, C0, Xc, zp, t);
    gemm_gate1<<<512, 256, 0, stream>>>(P[(t + 1) & 1], P[t & 1], Wp1, Bc1, C1,
                                        d_out, zp, flag, t);
  }
}

// Round 9
// 2059.610 us; speedup vs baseline: 1.1318x; 1.0147x over previous
//
#include <hip/hip_runtime.h>
#include <hip/hip_bf16.h>

// ConvLSTM (2 layers) on MI355X. R20 = R19 (best, 2090us) + gate0 M-doubled wave tile.
// Calibration: MfmaUtil(27%) x dur(149us) == dense-peak MFMA floor (39us) -> the whole
// gap is matrix-pipe idle. All scheduling/locality/occupancy levers bounced; the
// untouched knob is per-wave ILP. gate0 block: 256px(4 rows) x 128co, wave tile
// 128px x 64co, acc 8x4 (128 VGPR): 32 MFMAs (~160cy issue) per tap cover the
// 4 B-loads + 8 LDS reads; B traffic and barriers per pixel halve; halo staging
// 6 rows / 4 output rows (-25% DMA). Grid 1024 = 4nt x 256mt, XCD stripe: mt in
// [32x,32x+32) = 2 batches (same L2 footprint as R16). Spread staging kept (R19).
// gate1 unchanged. Kept: nt-grouped swizzle, tail-less DMA rows, zero page,
// P (B,64,64,160) fp16 [x(1),h0(128),h1(12),pad], 1-tap B reg prefetch, tanhf.

typedef __attribute__((ext_vector_type(8))) short short8;
typedef __attribute__((ext_vector_type(4))) float float4v;

#define CS 160
#define KTOT 1440         // 9*160
#define RSTR 2560         // LDS halo row stride (shorts) = 5 * 64 lanes * 8
#define BSTR 10240        // gate1 LDS buffer stride (shorts) = 4 * RSTR
#define BSTR6 15360       // gate0 LDS buffer stride (shorts) = 6 * RSTR

__device__ __forceinline__ float sigf(float x) { return 1.f / (1.f + __expf(-x)); }
__device__ __forceinline__ short f2hs(float v) {
  _Float16 h = (_Float16)v;
  return *(short*)&h;
}
__device__ __forceinline__ float bs2f(short s) {
  __hip_bfloat16 h; *(short*)&h = s; return __bfloat162float(h);
}
__device__ __forceinline__ short f2bs(float v) {
  __hip_bfloat16 h = __float2bfloat16(v);
  return *(short*)&h;
}

// async 16B global->LDS; per-lane lds ptr must equal uniform_base + lane*16
__device__ __forceinline__ void async_ld16(const short* g, short* l) {
  __builtin_amdgcn_global_load_lds(
      (const __attribute__((address_space(1))) unsigned int*)g,
      (__attribute__((address_space(3))) unsigned int*)l, 16, 0, 0);
}

// One 64-lane DMA slice (j in 0..4) of a halo row (66 px x 32 ch, row-major 32ch/px).
__device__ __forceinline__ void stage_one(const short* __restrict__ rowPtr, bool rowOK,
                                          short* dstRow, int lane,
                                          const short* __restrict__ zp, int j) {
  int e = j * 64 + lane;
  int px = e >> 2, v = e & 3;
  int xx = px - 1;
  bool ok = rowOK && (px < 66) && (xx >= 0) && (xx < 64);
  const short* g = ok ? (rowPtr + (size_t)xx * CS + v * 8) : zp;
  async_ld16(g, dstRow + e * 8);
}

// Full 5-DMA stage (prologue only).
__device__ __forceinline__ void stage_row(const short* __restrict__ rowPtr, bool rowOK,
                                          short* dstRow, int lane,
                                          const short* __restrict__ zp) {
  #pragma unroll
  for (int j = 0; j < 5; ++j) stage_one(rowPtr, rowOK, dstRow, lane, zp, j);
}

// ---- dtype detect: fp32 low-halves have uniform bits[14:7]; bf16 weights cluster ----
__global__ void detect_dtype(const unsigned short* __restrict__ w0, int* __restrict__ flag) {
  int lane = threadIdx.x;
  int cnt = 0;
  for (int i = 0; i < 4; ++i) {
    unsigned short u = w0[2 * (lane + 64 * i)];
    int e = (u >> 7) & 0xFF;
    unsigned long long b = __ballot(e >= 0xC0);
    cnt += __popcll(b);
  }
  if (lane == 0) *flag = (cnt > 32) ? 1 : 0;   // 1 = fp32 inputs
}

// ---- canonicalize x -> fp16 shorts (bf16->fp16 exact; sanitized) ----
__global__ void canon_x(const void* __restrict__ hist, short* __restrict__ Xc,
                        const int* __restrict__ flag) {
  int i = blockIdx.x * 256 + threadIdx.x;      // < 786432
  float v = (*flag) ? ((const float*)hist)[i] : bs2f(((const short*)hist)[i]);
  if (!isfinite(v) || fabsf(v) > 1e4f) v = 0.f;
  Xc[i] = f2hs(v);
}

__global__ void canon_b(const void* __restrict__ b0, const void* __restrict__ b1,
                        float* __restrict__ Bc0, float* __restrict__ Bc1,
                        const int* __restrict__ flag) {
  int i = blockIdx.x * 256 + threadIdx.x;
  int fl = *flag;
  if (i < 512) {
    float v = fl ? ((const float*)b0)[i] : bs2f(((const short*)b0)[i]);
    if (!isfinite(v) || fabsf(v) > 1e4f) v = 0.f;
    Bc0[i] = v;
  } else if (i < 560) {
    int j = i - 512;
    float v = fl ? ((const float*)b1)[j] : bs2f(((const short*)b1)[j]);
    if (!isfinite(v) || fabsf(v) > 1e4f) v = 0.f;
    Bc1[j] = v;
  }
}

// layer0 W0 (512,129,3,3) -> fp16 Wp[co][tap*160+c]: P-ch 0=x, 1..128=h0, else 0.
__global__ void prep_w0(const void* __restrict__ W0, short* __restrict__ Wp,
                        const int* __restrict__ flag) {
  int i = blockIdx.x * 256 + threadIdx.x;
  if (i >= 512 * KTOT) return;
  int fl = *flag;
  int co = i / KTOT, k = i - co * KTOT;
  int tap = k / CS, c = k - tap * CS;
  int ci = -1;
  if (c == 0) ci = 0;
  else if (c <= 128) ci = c;
  float w = 0.f;
  if (ci >= 0) {
    int widx = (co * 129 + ci) * 9 + tap;
    w = fl ? ((const float*)W0)[widx] : bs2f(((const short*)W0)[widx]);
    if (!isfinite(w) || fabsf(w) > 1e4f) w = 0.f;
  }
  Wp[i] = f2hs(w);
}

// layer1 W1 (48,140,3,3) -> fp16: P-ch 1..128=h0, 129..140=h1, else 0.
__global__ void prep_w1(const void* __restrict__ W1, short* __restrict__ Wp,
                        const int* __restrict__ flag) {
  int i = blockIdx.x * 256 + threadIdx.x;
  if (i >= 48 * KTOT) return;
  int fl = *flag;
  int co = i / KTOT, k = i - co * KTOT;
  int tap = k / CS, c = k - tap * CS;
  int ci = -1;
  if (c >= 1 && c <= 140) ci = c - 1;
  float w = 0.f;
  if (ci >= 0) {
    int widx = (co * 140 + ci) * 9 + tap;
    w = fl ? ((const float*)W1)[widx] : bs2f(((const short*)W1)[widx]);
    if (!isfinite(w) || fabsf(w) > 1e4f) w = 0.f;
  }
  Wp[i] = f2hs(w);
}

__global__ void fill_x0(const short* __restrict__ Xc, short* __restrict__ P0) {
  int p = blockIdx.x * 256 + threadIdx.x;      // b*4096 + pix
  int b = p >> 12, pix = p & 4095;
  P0[(size_t)p * CS] = Xc[b * 12 * 4096 + pix];
}

// ---- layer 0: M=256px (4 rows) x N=128co. Grid = 4 nt * 256 mt = 1024. ----
__global__ __launch_bounds__(256, 2) void gemm_gate0(
    const short* __restrict__ Pcur, short* __restrict__ Pnext,
    const short* __restrict__ Wp, const float* __restrict__ Bc0,
    float* __restrict__ C0, const short* __restrict__ Xc,
    const short* __restrict__ zp, int t) {
  // XCD stripe swizzle: XCD x owns mt in [32x,32x+32) (= 2 batches of P) for ALL nt.
  int pbx = blockIdx.x;
  int xcd = pbx & 7, i = pbx >> 3;             // i 0..127
  int mt = xcd * 32 + (i & 31);                // 0..255
  int nt = i >> 5;                             // 0..3
  int b = mt >> 4, y0 = (mt & 15) * 4;
  int tid = threadIdx.x, wave = tid >> 6, lane = tid & 63;
  int ln15 = lane & 15, quad = lane >> 4;
  int wm = wave & 1, wn = wave >> 1;           // wave tile: rows [wm*2, wm*2+1], co half wn
  int hc = nt * 32 + wn * 16 + ln15;

  __shared__ __align__(16) short halo[2 * BSTR6];   // dbuf, 61440 B

  float4v acc[8][4];
  #pragma unroll
  for (int i2 = 0; i2 < 8; ++i2)
    #pragma unroll
    for (int j = 0; j < 4; ++j) acc[i2][j] = (float4v){0.f, 0.f, 0.f, 0.f};

  // B frag addr (g, tap, c0): wbase + g*128*KTOT + tap*CS + c0
  const short* wbase = Wp + (size_t)hc * KTOT + quad * 8;
  short8 bcur[4], bnxt[4];
  #pragma unroll
  for (int g = 0; g < 4; ++g)
    bcur[g] = *(const short8*)(wbase + (size_t)g * 128 * KTOT);

  // 6 halo rows (y0-1 .. y0+4): wave w stages LDS row w; waves 0,1 also rows 4,5.
  int yyA = y0 - 1 + wave;
  bool okA = (yyA >= 0) && (yyA < 64);
  const short* baseA = Pcur + (size_t)((b * 64 + yyA) * 64) * CS;
  int yyB = y0 + 3 + wave;                     // rows 4,5 (waves 0,1 only)
  bool okB = (wave < 2) && (yyB < 64);
  const short* baseB = Pcur + (size_t)((b * 64 + yyB) * 64) * CS;

  stage_row(baseA, okA, halo + wave * RSTR, lane, zp);
  if (wave < 2) stage_row(baseB, okB, halo + (4 + wave) * RSTR, lane, zp);
  __syncthreads();

  for (int ch = 0; ch < 5; ++ch) {
    int c0 = ch * 32;
    const short* cur = halo + (ch & 1) * BSTR6;
    short* nd = halo + ((ch + 1) & 1) * BSTR6;
    const short* srcA = baseA + c0 + 32;
    const short* srcB = baseB + c0 + 32;
    #pragma unroll
    for (int tap = 0; tap < 9; ++tap) {
      int dy = tap / 3, dx = tap - dy * 3;
      // spread staging (R19): <=2 DMA slices per wave per tap, taps 0..4
      if (ch < 4 && tap < 5) {
        stage_one(srcA, okA, nd + wave * RSTR, lane, zp, tap);
        if (wave < 2) stage_one(srcB, okB, nd + (4 + wave) * RSTR, lane, zp, tap);
      }
      // prefetch next tap's (or next chunk's tap-0) B fragments
      int ntap = (tap < 8) ? tap + 1 : 0;
      int nc0 = (tap < 8) ? c0 : ((ch < 4) ? c0 + 32 : c0);
      #pragma unroll
      for (int g = 0; g < 4; ++g)
        bnxt[g] = *(const short8*)(wbase + (size_t)g * 128 * KTOT + ntap * CS + nc0);

      short8 af[8];
      #pragma unroll
      for (int mf = 0; mf < 8; ++mf)
        af[mf] = *(const short8*)&cur[(wm * 2 + (mf >> 2) + dy) * RSTR
                                      + ((mf & 3) * 16 + ln15 + dx) * 32 + quad * 8];
      #pragma unroll
      for (int g = 0; g < 4; ++g)
        #pragma unroll
        for (int mf = 0; mf < 8; ++mf)
          acc[mf][g] = __builtin_amdgcn_mfma_f32_16x16x32_f16(af[mf], bcur[g], acc[mf][g], 0, 0, 0);
      #pragma unroll
      for (int g = 0; g < 4; ++g) bcur[g] = bnxt[g];
    }
    __syncthreads();
  }

  // epilogue: all 4 gates in-register per (pix,hc); 8 mf = 2 rows x 4 x-frags
  float bi = Bc0[hc], bff = Bc0[128 + hc], bo = Bc0[256 + hc], bg = Bc0[384 + hc];
  #pragma unroll
  for (int mf = 0; mf < 8; ++mf) {
    int row = y0 + wm * 2 + (mf >> 2);
    int pixRow = (b * 64 + row) * 64;
    #pragma unroll
    for (int r = 0; r < 4; ++r) {
      int x = (mf & 3) * 16 + quad * 4 + r;    // C/D row = quad*4 + reg
      int pix = pixRow + x;
      float zi = acc[mf][0][r] + bi;
      float zf = acc[mf][1][r] + bff;
      float zo = acc[mf][2][r] + bo;
      float zg = acc[mf][3][r] + bg;
      float cprev = C0[(size_t)pix * 128 + hc];
      float cn = sigf(zf) * cprev + sigf(zi) * tanhf(zg);
      float hn = sigf(zo) * tanhf(cn);
      C0[(size_t)pix * 128 + hc] = cn;
      Pnext[(size_t)pix * CS + 1 + hc] = f2hs(hn);
    }
  }
  if (nt == 0 && t < 11) {
    int rr = tid >> 6, x = tid & 63;           // 4 rows x 64 px
    int yw = y0 + rr;
    Pnext[(size_t)((b * 64 + yw) * 64 + x) * CS] = Xc[(b * 12 + t + 1) * 4096 + yw * 64 + x];
  }
}

// ---- layer 1: M=128px (2 rows) x N=48co. Grid 512. B register-prefetch. ----
__global__ __launch_bounds__(256, 2) void gemm_gate1(
    const short* __restrict__ Prd, short* __restrict__ Pwr,
    const short* __restrict__ Wp, const float* __restrict__ Bc1,
    float* __restrict__ C1, void* __restrict__ outp,
    const short* __restrict__ zp, const int* __restrict__ flagp, int t) {
  // XCD stripe swizzle: XCD x owns bid in [64x, 64x+64) = 2 batches (L2-fit halos).
  int pbx = blockIdx.x;
  int bid = (pbx & 7) * 64 + (pbx >> 3);
  int b = bid >> 5, y0 = (bid & 31) * 2;
  int tid = threadIdx.x, wave = tid >> 6, lane = tid & 63;
  int ln15 = lane & 15, quad = lane >> 4;
  int wr = wave >> 1, wh = wave & 1;
  int flagv = *flagp;

  __shared__ __align__(16) short halo[2 * BSTR];   // 40960 B

  float4v acc[2][3];
  #pragma unroll
  for (int i = 0; i < 2; ++i)
    #pragma unroll
    for (int j = 0; j < 3; ++j) acc[i][j] = (float4v){0.f, 0.f, 0.f, 0.f};

  int yy = y0 - 1 + wave;
  bool rowOK = (yy >= 0) && (yy < 64);
  const short* rowBase = Prd + (size_t)((b * 64 + yy) * 64) * CS;

  const short* wbase = Wp + (size_t)ln15 * KTOT + quad * 8;
  short8 bcur[3], bnxt[3];
  #pragma unroll
  for (int nf = 0; nf < 3; ++nf)
    bcur[nf] = *(const short8*)(wbase + (size_t)nf * 16 * KTOT);

  stage_row(rowBase, rowOK, halo + wave * RSTR, lane, zp);
  __syncthreads();

  for (int ch = 0; ch < 5; ++ch) {
    int c0 = ch * 32;
    const short* cur = halo + (ch & 1) * BSTR;
    short* nxtDst = halo + ((ch + 1) & 1) * BSTR + wave * RSTR;
    const short* nxtSrc = rowBase + c0 + 32;
    #pragma unroll
    for (int tap = 0; tap < 9; ++tap) {
      int dy = tap / 3, dx = tap - dy * 3;
      if (ch < 4 && tap < 5)
        stage_one(nxtSrc, rowOK, nxtDst, lane, zp, tap);
      int ntap = (tap < 8) ? tap + 1 : 0;
      int nc0 = (tap < 8) ? c0 : ((ch < 4) ? c0 + 32 : c0);
      #pragma unroll
      for (int nf = 0; nf < 3; ++nf)
        bnxt[nf] = *(const short8*)(wbase + (size_t)nf * 16 * KTOT + ntap * CS + nc0);

      short8 af[2];
      #pragma unroll
      for (int mf = 0; mf < 2; ++mf)
        af[mf] = *(const short8*)&cur[(wr + dy) * RSTR + (wh * 32 + mf * 16 + ln15 + dx) * 32
                                      + quad * 8];
      #pragma unroll
      for (int nf = 0; nf < 3; ++nf)
        #pragma unroll
        for (int mf = 0; mf < 2; ++mf)
          acc[mf][nf] = __builtin_amdgcn_mfma_f32_16x16x32_f16(af[mf], bcur[nf], acc[mf][nf], 0, 0, 0);
      #pragma unroll
      for (int nf = 0; nf < 3; ++nf) bcur[nf] = bnxt[nf];
    }
    __syncthreads();
  }

  // z -> LDS (reuse halo: 128*48 fp32 = 24576 B), then gate pass
  float* zbuf = (float*)halo;
  #pragma unroll
  for (int mf = 0; mf < 2; ++mf)
    #pragma unroll
    for (int nf = 0; nf < 3; ++nf)
      #pragma unroll
      for (int r = 0; r < 4; ++r) {
        int pxl = wr * 64 + wh * 32 + mf * 16 + quad * 4 + r;
        zbuf[pxl * 48 + nf * 16 + ln15] = acc[mf][nf][r];
      }
  __syncthreads();

  #pragma unroll
  for (int k = 0; k < 6; ++k) {
    int id = k * 256 + tid;
    int hc = id >> 7, pxl = id & 127;
    float zi = zbuf[pxl * 48 + hc]      + Bc1[hc];
    float zf = zbuf[pxl * 48 + 12 + hc] + Bc1[12 + hc];
    float zo = zbuf[pxl * 48 + 24 + hc] + Bc1[24 + hc];
    float zg = zbuf[pxl * 48 + 36 + hc] + Bc1[36 + hc];
    int y = y0 + (pxl >> 6), x = pxl & 63;
    int pix = (b * 64 + y) * 64 + x;
    float cprev = C1[(size_t)pix * 12 + hc];
    float cn = sigf(zf) * cprev + sigf(zi) * tanhf(zg);
    float hn = sigf(zo) * tanhf(cn);
    C1[(size_t)pix * 12 + hc] = cn;
    Pwr[(size_t)pix * CS + 129 + hc] = f2hs(hn);
    if (t == 11) {
      int oidx = (b * 12 + hc) * 4096 + y * 64 + x;
      if (flagv) ((float*)outp)[oidx] = hn;
      else ((short*)outp)[oidx] = f2bs(hn);
    }
  }
}

extern "C" void kernel_launch(void* const* d_in, const int* in_sizes, int n_in,
                              void* d_out, int out_size, void* d_ws, size_t ws_size,
                              hipStream_t stream) {
  const void* hist = d_in[0];                  // (16,12,4096,1)
  const void* W0 = d_in[2];                    // (512,129,3,3)
  const void* b0 = d_in[3];
  const void* W1 = d_in[4];                    // (48,140,3,3)
  const void* b1 = d_in[5];

  char* ws = (char*)d_ws;
  const size_t PszB = (size_t)16 * 4096 * CS * 2;     // 20,971,520
  short* P[2] = {(short*)ws, (short*)(ws + PszB)};
  float* C0 = (float*)(ws + 2 * PszB);                // 33,554,432
  const size_t C0e = 2 * PszB + 33554432;
  float* C1 = (float*)(ws + C0e);                     // 3,145,728
  const size_t C1e = C0e + 3145728;
  short* zp = (short*)(ws + C1e);                     // 256 B zero page
  const size_t zpe = C1e + 256;
  short* Xc = (short*)(ws + zpe);                     // 1,572,864
  const size_t Xce = zpe + 1572864;
  short* Wp0 = (short*)(ws + Xce);                    // 512*1440*2 = 1,474,560
  const size_t W0e = Xce + (size_t)512 * KTOT * 2;
  short* Wp1 = (short*)(ws + W0e);                    // 48*1440*2 = 138,240
  const size_t W1e = W0e + (size_t)48 * KTOT * 2;
  float* Bc0 = (float*)(ws + W1e);                    // 2048
  float* Bc1 = (float*)(ws + W1e + 2048);             // 192
  int* flag = (int*)(ws + W1e + 2048 + 192);          // total ~82 MiB

  hipMemsetAsync(ws, 0, zpe, stream);                 // P pair + C0 + C1 + zero page
  detect_dtype<<<1, 64, 0, stream>>>((const unsigned short*)W0, flag);
  canon_x<<<3072, 256, 0, stream>>>(hist, Xc, flag);
  canon_b<<<3, 256, 0, stream>>>(b0, b1, Bc0, Bc1, flag);
  prep_w0<<<(512 * KTOT + 255) / 256, 256, 0, stream>>>(W0, Wp0, flag);
  prep_w1<<<(48 * KTOT + 255) / 256, 256, 0, stream>>>(W1, Wp1, flag);
  fill_x0<<<256, 256, 0, stream>>>(Xc, P[0]);

  for (int t = 0; t < 12; ++t) {
    gemm_gate0<<<1024, 256, 0, stream>>>(P[t & 1], P[(t + 1) & 1], Wp0, Bc0, C0, Xc, zp, t);
    gemm_gate1<<<512, 256, 0, stream>>>(P[(t + 1) & 1], P[t & 1], Wp1, Bc1, C1,
                                        d_out, zp, flag, t);
  }
}

// Round 10
// 1933.535 us; speedup vs baseline: 1.2056x; 1.0652x over previous
//
#include <hip/hip_runtime.h>
#include <hip/hip_bf16.h>

// ConvLSTM (2 layers) on MI355X. R21 = R20 (best, 2060us) + dead-K removal, stride-safe.
// R13/R14's dead-K regression is attributed to CS=128's 256B power-of-2 pixel stride
// (+ bad swizzle grouping), NOT the tap-packed x phase. R21 keeps CS=160 (320B stride)
// and repacks P as [h0: ch0..127][h1: ch128..139][pad 20] -- x leaves P entirely.
// gate0: 4 pure-h0 chunks (36 taps) + 1 tap-packed x MFMA phase (A=Xtap[t][pix][16],
// k=taps, B zero for k>=16 via zero page). x-operand loads issued BEFORE staging DMAs
// (in-order vmcnt: consuming them doesn't drain staging). MFMA/wave 1440->1184 (-18%),
// staging -20%, B-loads -20%. Pnext h0 writes now byte-aligned [0,256) (kills the
// R20 write amplification, WRITE 93MB). gate1: unchanged except weight remap (ci=c)
// and h1 at ch128. Kept: R20 4-row M-tile (acc 8x4), R19 spread staging, R16 XCD
// stripe swizzle, tail-less DMA rows, zero page, launch_bounds(256,2), tanhf.

typedef __attribute__((ext_vector_type(8))) short short8;
typedef __attribute__((ext_vector_type(4))) float float4v;

#define CS 160
#define KT0 1152          // gate0 K = 9*128 (pure h0)
#define KTOT 1440         // gate1 K = 9*160
#define RSTR 2560         // LDS halo row stride (shorts) = 5 * 64 lanes * 8
#define BSTR 10240        // gate1 LDS buffer stride (shorts) = 4 * RSTR
#define BSTR6 15360       // gate0 LDS buffer stride (shorts) = 6 * RSTR

__device__ __forceinline__ float sigf(float x) { return 1.f / (1.f + __expf(-x)); }
__device__ __forceinline__ short f2hs(float v) {
  _Float16 h = (_Float16)v;
  return *(short*)&h;
}
__device__ __forceinline__ float bs2f(short s) {
  __hip_bfloat16 h; *(short*)&h = s; return __bfloat162float(h);
}
__device__ __forceinline__ short f2bs(float v) {
  __hip_bfloat16 h = __float2bfloat16(v);
  return *(short*)&h;
}

// async 16B global->LDS; per-lane lds ptr must equal uniform_base + lane*16
__device__ __forceinline__ void async_ld16(const short* g, short* l) {
  __builtin_amdgcn_global_load_lds(
      (const __attribute__((address_space(1))) unsigned int*)g,
      (__attribute__((address_space(3))) unsigned int*)l, 16, 0, 0);
}

// One 64-lane DMA slice (j in 0..4) of a halo row (66 px x 32 ch, row-major 32ch/px).
__device__ __forceinline__ void stage_one(const short* __restrict__ rowPtr, bool rowOK,
                                          short* dstRow, int lane,
                                          const short* __restrict__ zp, int j) {
  int e = j * 64 + lane;
  int px = e >> 2, v = e & 3;
  int xx = px - 1;
  bool ok = rowOK && (px < 66) && (xx >= 0) && (xx < 64);
  const short* g = ok ? (rowPtr + (size_t)xx * CS + v * 8) : zp;
  async_ld16(g, dstRow + e * 8);
}

// Full 5-DMA stage (prologue only).
__device__ __forceinline__ void stage_row(const short* __restrict__ rowPtr, bool rowOK,
                                          short* dstRow, int lane,
                                          const short* __restrict__ zp) {
  #pragma unroll
  for (int j = 0; j < 5; ++j) stage_one(rowPtr, rowOK, dstRow, lane, zp, j);
}

// ---- dtype detect: fp32 low-halves have uniform bits[14:7]; bf16 weights cluster ----
__global__ void detect_dtype(const unsigned short* __restrict__ w0, int* __restrict__ flag) {
  int lane = threadIdx.x;
  int cnt = 0;
  for (int i = 0; i < 4; ++i) {
    unsigned short u = w0[2 * (lane + 64 * i)];
    int e = (u >> 7) & 0xFF;
    unsigned long long b = __ballot(e >= 0xC0);
    cnt += __popcll(b);
  }
  if (lane == 0) *flag = (cnt > 32) ? 1 : 0;   // 1 = fp32 inputs
}

__global__ void canon_b(const void* __restrict__ b0, const void* __restrict__ b1,
                        float* __restrict__ Bc0, float* __restrict__ Bc1,
                        const int* __restrict__ flag) {
  int i = blockIdx.x * 256 + threadIdx.x;
  int fl = *flag;
  if (i < 512) {
    float v = fl ? ((const float*)b0)[i] : bs2f(((const short*)b0)[i]);
    if (!isfinite(v) || fabsf(v) > 1e4f) v = 0.f;
    Bc0[i] = v;
  } else if (i < 560) {
    int j = i - 512;
    float v = fl ? ((const float*)b1)[j] : bs2f(((const short*)b1)[j]);
    if (!isfinite(v) || fabsf(v) > 1e4f) v = 0.f;
    Bc1[j] = v;
  }
}

__device__ __forceinline__ float ldw(const void* W, int idx, int fl) {
  float w = fl ? ((const float*)W)[idx] : bs2f(((const short*)W)[idx]);
  if (!isfinite(w) || fabsf(w) > 1e4f) w = 0.f;
  return w;
}

// layer0 h0 weights: Wp0[co][tap*128+c] = W0[co][1+c][tap]  (512 x 1152)
__global__ void prep_w0(const void* __restrict__ W0, short* __restrict__ Wp,
                        const int* __restrict__ flag) {
  int i = blockIdx.x * 256 + threadIdx.x;
  if (i >= 512 * KT0) return;
  int fl = *flag;
  int co = i / KT0, k = i - co * KT0;
  int tap = k >> 7, c = k & 127;
  Wp[i] = f2hs(ldw(W0, (co * 129 + 1 + c) * 9 + tap, fl));
}

// layer0 x weights: Wx[co][16], k<9 -> W0[co][0][k], else 0  (512 x 16)
__global__ void prep_wx(const void* __restrict__ W0, short* __restrict__ Wx,
                        const int* __restrict__ flag) {
  int i = blockIdx.x * 256 + threadIdx.x;
  if (i >= 512 * 16) return;
  int fl = *flag;
  int co = i >> 4, k = i & 15;
  float w = (k < 9) ? ldw(W0, (co * 129) * 9 + k, fl) : 0.f;
  Wx[i] = f2hs(w);
}

// layer1 weights: Wp1[co][tap*160+c]: c<140 -> W1[co][c][tap] (h0 at P-ch0..127,
// h1 at P-ch128..139), else 0.  (48 x 1440)
__global__ void prep_w1(const void* __restrict__ W1, short* __restrict__ Wp,
                        const int* __restrict__ flag) {
  int i = blockIdx.x * 256 + threadIdx.x;
  if (i >= 48 * KTOT) return;
  int fl = *flag;
  int co = i / KTOT, k = i - co * KTOT;
  int tap = k / CS, c = k - tap * CS;
  float w = (c < 140) ? ldw(W1, (co * 140 + c) * 9 + tap, fl) : 0.f;
  Wp[i] = f2hs(w);
}

// Xtap[t][p][16]: k<9 = sanitized x[t] at tap-shifted pixel (0 at borders), k>=9 = 0.
__global__ void prep_xtap(const void* __restrict__ hist, short* __restrict__ Xtap,
                          const int* __restrict__ flag) {
  int i = blockIdx.x * 256 + threadIdx.x;      // < 786432 = 12*65536
  int t = i >> 16, p = i & 65535;
  int b = p >> 12, pix = p & 4095, y = pix >> 6, x = pix & 63;
  int fl = *flag;
  short8 lo = {0, 0, 0, 0, 0, 0, 0, 0}, hi = {0, 0, 0, 0, 0, 0, 0, 0};
  #pragma unroll
  for (int k = 0; k < 9; ++k) {
    int dy = k / 3, dx = k - dy * 3;
    int yy = y + dy - 1, xx = x + dx - 1;
    float f = 0.f;
    if (yy >= 0 && yy < 64 && xx >= 0 && xx < 64) {
      int hidx = (b * 12 + t) * 4096 + yy * 64 + xx;
      f = fl ? ((const float*)hist)[hidx] : bs2f(((const short*)hist)[hidx]);
      if (!isfinite(f) || fabsf(f) > 1e4f) f = 0.f;
    }
    if (k < 8) lo[k] = f2hs(f); else hi[k - 8] = f2hs(f);
  }
  *(short8*)(Xtap + (size_t)i * 16) = lo;
  *(short8*)(Xtap + (size_t)i * 16 + 8) = hi;
}

// ---- layer 0: M=256px (4 rows) x N=128co. Grid = 4 nt * 256 mt = 1024. ----
__global__ __launch_bounds__(256, 2) void gemm_gate0(
    const short* __restrict__ Pcur, short* __restrict__ Pnext,
    const short* __restrict__ Wp, const short* __restrict__ Wx,
    const float* __restrict__ Bc0, float* __restrict__ C0,
    const short* __restrict__ Xtap, const short* __restrict__ zp, int t) {
  // XCD stripe swizzle: XCD x owns mt in [32x,32x+32) (= 2 batches of P) for ALL nt.
  int pbx = blockIdx.x;
  int xcd = pbx & 7, i = pbx >> 3;             // i 0..127
  int mt = xcd * 32 + (i & 31);                // 0..255
  int nt = i >> 5;                             // 0..3
  int b = mt >> 4, y0 = (mt & 15) * 4;
  int tid = threadIdx.x, wave = tid >> 6, lane = tid & 63;
  int ln15 = lane & 15, quad = lane >> 4;
  int wm = wave & 1, wn = wave >> 1;           // wave tile: rows [wm*2, wm*2+1], co half wn
  int hc = nt * 32 + wn * 16 + ln15;

  __shared__ __align__(16) short halo[2 * BSTR6];   // dbuf, 61440 B

  float4v acc[8][4];
  #pragma unroll
  for (int i2 = 0; i2 < 8; ++i2)
    #pragma unroll
    for (int j = 0; j < 4; ++j) acc[i2][j] = (float4v){0.f, 0.f, 0.f, 0.f};

  // B frag addr (g, tap, c0): wbase + g*128*KT0 + tap*128 + c0
  const short* wbase = Wp + (size_t)hc * KT0 + quad * 8;
  short8 bcur[4], bnxt[4];
  #pragma unroll
  for (int g = 0; g < 4; ++g)
    bcur[g] = *(const short8*)(wbase + (size_t)g * 128 * KT0);

  // 6 halo rows (y0-1 .. y0+4): wave w stages LDS row w; waves 0,1 also rows 4,5.
  int yyA = y0 - 1 + wave;
  bool okA = (yyA >= 0) && (yyA < 64);
  const short* baseA = Pcur + (size_t)((b * 64 + yyA) * 64) * CS;
  int yyB = y0 + 3 + wave;                     // rows 4,5 (waves 0,1 only)
  bool okB = (wave < 2) && (yyB < 64);
  const short* baseB = Pcur + (size_t)((b * 64 + yyB) * 64) * CS;

  // x-phase operand loads FIRST: consuming them later only drains the vmcnt FIFO
  // up to here (no staging DMA is ahead of them).
  bool hiQ = quad >= 2;
  short8 ax[8], bxr[4];
  #pragma unroll
  for (int mf = 0; mf < 8; ++mf) {
    int row = y0 + wm * 2 + (mf >> 2);
    int pixB = (b * 64 + row) * 64 + (mf & 3) * 16 + ln15;
    ax[mf] = *(const short8*)(Xtap + ((size_t)t * 65536 + pixB) * 16 + (quad & 1) * 8);
  }
  #pragma unroll
  for (int g = 0; g < 4; ++g) {
    const short* wxp = Wx + (size_t)(g * 128 + hc) * 16 + (quad & 1) * 8;
    bxr[g] = *(const short8*)(hiQ ? zp : wxp);
  }

  stage_row(baseA, okA, halo + wave * RSTR, lane, zp);
  if (wave < 2) stage_row(baseB, okB, halo + (4 + wave) * RSTR, lane, zp);

  // tap-packed x phase: K=32 MFMA, k=taps (0..8 live); B zeros for k>=16 kill the
  // garbage A upper half. Runs while staging DMAs are in flight.
  #pragma unroll
  for (int g = 0; g < 4; ++g)
    #pragma unroll
    for (int mf = 0; mf < 8; ++mf)
      acc[mf][g] = __builtin_amdgcn_mfma_f32_16x16x32_f16(ax[mf], bxr[g], acc[mf][g], 0, 0, 0);
  __syncthreads();

  for (int ch = 0; ch < 4; ++ch) {
    int c0 = ch * 32;
    const short* cur = halo + (ch & 1) * BSTR6;
    short* nd = halo + ((ch + 1) & 1) * BSTR6;
    const short* srcA = baseA + c0 + 32;
    const short* srcB = baseB + c0 + 32;
    #pragma unroll
    for (int tap = 0; tap < 9; ++tap) {
      int dy = tap / 3, dx = tap - dy * 3;
      // spread staging (R19): <=2 DMA slices per wave per tap, taps 0..4
      if (ch < 3 && tap < 5) {
        stage_one(srcA, okA, nd + wave * RSTR, lane, zp, tap);
        if (wave < 2) stage_one(srcB, okB, nd + (4 + wave) * RSTR, lane, zp, tap);
      }
      // prefetch next tap's (or next chunk's tap-0) B fragments
      int ntap = (tap < 8) ? tap + 1 : 0;
      int nc0 = (tap < 8) ? c0 : ((ch < 3) ? c0 + 32 : c0);
      #pragma unroll
      for (int g = 0; g < 4; ++g)
        bnxt[g] = *(const short8*)(wbase + (size_t)g * 128 * KT0 + ntap * 128 + nc0);

      short8 af[8];
      #pragma unroll
      for (int mf = 0; mf < 8; ++mf)
        af[mf] = *(const short8*)&cur[(wm * 2 + (mf >> 2) + dy) * RSTR
                                      + ((mf & 3) * 16 + ln15 + dx) * 32 + quad * 8];
      #pragma unroll
      for (int g = 0; g < 4; ++g)
        #pragma unroll
        for (int mf = 0; mf < 8; ++mf)
          acc[mf][g] = __builtin_amdgcn_mfma_f32_16x16x32_f16(af[mf], bcur[g], acc[mf][g], 0, 0, 0);
      #pragma unroll
      for (int g = 0; g < 4; ++g) bcur[g] = bnxt[g];
    }
    __syncthreads();
  }

  // epilogue: all 4 gates in-register per (pix,hc); 8 mf = 2 rows x 4 x-frags.
  // h0 write at ch0..127: bytes [0,256) of the 320B pixel -- sector-aligned.
  float bi = Bc0[hc], bff = Bc0[128 + hc], bo = Bc0[256 + hc], bg = Bc0[384 + hc];
  #pragma unroll
  for (int mf = 0; mf < 8; ++mf) {
    int row = y0 + wm * 2 + (mf >> 2);
    int pixRow = (b * 64 + row) * 64;
    #pragma unroll
    for (int r = 0; r < 4; ++r) {
      int x = (mf & 3) * 16 + quad * 4 + r;    // C/D row = quad*4 + reg
      int pix = pixRow + x;
      float zi = acc[mf][0][r] + bi;
      float zf = acc[mf][1][r] + bff;
      float zo = acc[mf][2][r] + bo;
      float zg = acc[mf][3][r] + bg;
      float cprev = C0[(size_t)pix * 128 + hc];
      float cn = sigf(zf) * cprev + sigf(zi) * tanhf(zg);
      float hn = sigf(zo) * tanhf(cn);
      C0[(size_t)pix * 128 + hc] = cn;
      Pnext[(size_t)pix * CS + hc] = f2hs(hn);
    }
  }
}

// ---- layer 1: M=128px (2 rows) x N=48co. Grid 512. B register-prefetch. ----
__global__ __launch_bounds__(256, 2) void gemm_gate1(
    const short* __restrict__ Prd, short* __restrict__ Pwr,
    const short* __restrict__ Wp, const float* __restrict__ Bc1,
    float* __restrict__ C1, void* __restrict__ outp,
    const short* __restrict__ zp, const int* __restrict__ flagp, int t) {
  // XCD stripe swizzle: XCD x owns bid in [64x, 64x+64) = 2 batches (L2-fit halos).
  int pbx = blockIdx.x;
  int bid = (pbx & 7) * 64 + (pbx >> 3);
  int b = bid >> 5, y0 = (bid & 31) * 2;
  int tid = threadIdx.x, wave = tid >> 6, lane = tid & 63;
  int ln15 = lane & 15, quad = lane >> 4;
  int wr = wave >> 1, wh = wave & 1;
  int flagv = *flagp;

  __shared__ __align__(16) short halo[2 * BSTR];   // 40960 B

  float4v acc[2][3];
  #pragma unroll
  for (int i = 0; i < 2; ++i)
    #pragma unroll
    for (int j = 0; j < 3; ++j) acc[i][j] = (float4v){0.f, 0.f, 0.f, 0.f};

  int yy = y0 - 1 + wave;
  bool rowOK = (yy >= 0) && (yy < 64);
  const short* rowBase = Prd + (size_t)((b * 64 + yy) * 64) * CS;

  const short* wbase = Wp + (size_t)ln15 * KTOT + quad * 8;
  short8 bcur[3], bnxt[3];
  #pragma unroll
  for (int nf = 0; nf < 3; ++nf)
    bcur[nf] = *(const short8*)(wbase + (size_t)nf * 16 * KTOT);

  stage_row(rowBase, rowOK, halo + wave * RSTR, lane, zp);
  __syncthreads();

  for (int ch = 0; ch < 5; ++ch) {
    int c0 = ch * 32;
    const short* cur = halo + (ch & 1) * BSTR;
    short* nxtDst = halo + ((ch + 1) & 1) * BSTR + wave * RSTR;
    const short* nxtSrc = rowBase + c0 + 32;
    #pragma unroll
    for (int tap = 0; tap < 9; ++tap) {
      int dy = tap / 3, dx = tap - dy * 3;
      if (ch < 4 && tap < 5)
        stage_one(nxtSrc, rowOK, nxtDst, lane, zp, tap);
      int ntap = (tap < 8) ? tap + 1 : 0;
      int nc0 = (tap < 8) ? c0 : ((ch < 4) ? c0 + 32 : c0);
      #pragma unroll
      for (int nf = 0; nf < 3; ++nf)
        bnxt[nf] = *(const short8*)(wbase + (size_t)nf * 16 * KTOT + ntap * CS + nc0);

      short8 af[2];
      #pragma unroll
      for (int mf = 0; mf < 2; ++mf)
        af[mf] = *(const short8*)&cur[(wr + dy) * RSTR + (wh * 32 + mf * 16 + ln15 + dx) * 32
                                      + quad * 8];
      #pragma unroll
      for (int nf = 0; nf < 3; ++nf)
        #pragma unroll
        for (int mf = 0; mf < 2; ++mf)
          acc[mf][nf] = __builtin_amdgcn_mfma_f32_16x16x32_f16(af[mf], bcur[nf], acc[mf][nf], 0, 0, 0);
      #pragma unroll
      for (int nf = 0; nf < 3; ++nf) bcur[nf] = bnxt[nf];
    }
    __syncthreads();
  }

  // z -> LDS (reuse halo: 128*48 fp32 = 24576 B), then gate pass
  float* zbuf = (float*)halo;
  #pragma unroll
  for (int mf = 0; mf < 2; ++mf)
    #pragma unroll
    for (int nf = 0; nf < 3; ++nf)
      #pragma unroll
      for (int r = 0; r < 4; ++r) {
        int pxl = wr * 64 + wh * 32 + mf * 16 + quad * 4 + r;
        zbuf[pxl * 48 + nf * 16 + ln15] = acc[mf][nf][r];
      }
  __syncthreads();

  #pragma unroll
  for (int k = 0; k < 6; ++k) {
    int id = k * 256 + tid;
    int hc = id >> 7, pxl = id & 127;
    float zi = zbuf[pxl * 48 + hc]      + Bc1[hc];
    float zf = zbuf[pxl * 48 + 12 + hc] + Bc1[12 + hc];
    float zo = zbuf[pxl * 48 + 24 + hc] + Bc1[24 + hc];
    float zg = zbuf[pxl * 48 + 36 + hc] + Bc1[36 + hc];
    int y = y0 + (pxl >> 6), x = pxl & 63;
    int pix = (b * 64 + y) * 64 + x;
    float cprev = C1[(size_t)pix * 12 + hc];
    float cn = sigf(zf) * cprev + sigf(zi) * tanhf(zg);
    float hn = sigf(zo) * tanhf(cn);
    C1[(size_t)pix * 12 + hc] = cn;
    Pwr[(size_t)pix * CS + 128 + hc] = f2hs(hn);   // h1 at ch128..139
    if (t == 11) {
      int oidx = (b * 12 + hc) * 4096 + y * 64 + x;
      if (flagv) ((float*)outp)[oidx] = hn;
      else ((short*)outp)[oidx] = f2bs(hn);
    }
  }
}

extern "C" void kernel_launch(void* const* d_in, const int* in_sizes, int n_in,
                              void* d_out, int out_size, void* d_ws, size_t ws_size,
                              hipStream_t stream) {
  const void* hist = d_in[0];                  // (16,12,4096,1)
  const void* W0 = d_in[2];                    // (512,129,3,3)
  const void* b0 = d_in[3];
  const void* W1 = d_in[4];                    // (48,140,3,3)
  const void* b1 = d_in[5];

  char* ws = (char*)d_ws;
  const size_t PszB = (size_t)16 * 4096 * CS * 2;     // 20,971,520
  short* P[2] = {(short*)ws, (short*)(ws + PszB)};
  float* C0 = (float*)(ws + 2 * PszB);                // 33,554,432
  const size_t C0e = 2 * PszB + 33554432;
  float* C1 = (float*)(ws + C0e);                     // 3,145,728
  const size_t C1e = C0e + 3145728;
  short* zp = (short*)(ws + C1e);                     // 256 B zero page
  const size_t zpe = C1e + 256;                       // memset to here
  short* Xtap = (short*)(ws + zpe);                   // 12*65536*16*2 = 25,165,824
  const size_t Xte = zpe + (size_t)12 * 65536 * 16 * 2;
  short* Wp0 = (short*)(ws + Xte);                    // 512*1152*2 = 1,179,648
  const size_t W0e = Xte + (size_t)512 * KT0 * 2;
  short* Wx0 = (short*)(ws + W0e);                    // 512*16*2 = 16,384
  const size_t Wxe = W0e + 512 * 16 * 2;
  short* Wp1 = (short*)(ws + Wxe);                    // 48*1440*2 = 138,240
  const size_t W1e = Wxe + (size_t)48 * KTOT * 2;
  float* Bc0 = (float*)(ws + W1e);                    // 2048
  float* Bc1 = (float*)(ws + W1e + 2048);             // 192
  int* flag = (int*)(ws + W1e + 2048 + 192);          // total ~105 MiB

  hipMemsetAsync(ws, 0, zpe, stream);                 // P pair + C0 + C1 + zero page
  detect_dtype<<<1, 64, 0, stream>>>((const unsigned short*)W0, flag);
  canon_b<<<3, 256, 0, stream>>>(b0, b1, Bc0, Bc1, flag);
  prep_w0<<<(512 * KT0 + 255) / 256, 256, 0, stream>>>(W0, Wp0, flag);
  prep_wx<<<32, 256, 0, stream>>>(W0, Wx0, flag);
  prep_w1<<<(48 * KTOT + 255) / 256, 256, 0, stream>>>(W1, Wp1, flag);
  prep_xtap<<<3072, 256, 0, stream>>>(hist, Xtap, flag);

  for (int t = 0; t < 12; ++t) {
    gemm_gate0<<<1024, 256, 0, stream>>>(P[t & 1], P[(t + 1) & 1], Wp0, Wx0, Bc0, C0,
                                         Xtap, zp, t);
    gemm_gate1<<<512, 256, 0, stream>>>(P[(t + 1) & 1], P[t & 1], Wp1, Bc1, C1,
                                        d_out, zp, flag, t);
  }
}